// Round 1
// baseline (1261.158 us; speedup 1.0000x reference)
//
#include <hip/hip_runtime.h>
#include <math.h>

// Problem constants (from reference): N=64, C=256, T=64, V=25
#define NN 64
#define CC 256
#define TT 64
#define VV 25
#define VP 28   // padded LDS row stride: 28*4=112 B, 16B-aligned for ds_read_b128

// Fully fused 4-block ODE function. Key fact: for fixed (n,t) the whole
// 4-block chain depends only on the C x V slab x[n,:,t,:]:
//   - A-einsum mixes the V (joint) dim within each (n,c,t) row
//   - w-einsum mixes the C (channel) dim within each (n,t,v) column
// So one workgroup owns one (n,t) slab end-to-end; zero intermediate HBM.
__global__ __launch_bounds__(256, 2) void ode_fused(
    const float* __restrict__ x, const float* __restrict__ Amat,
    const float* __restrict__ w1, const float* __restrict__ b1,
    const float* __restrict__ w2, const float* __restrict__ b2,
    const float* __restrict__ w3, const float* __restrict__ b3,
    const float* __restrict__ w4, const float* __restrict__ b4,
    float* __restrict__ out)
{
    __shared__ float sA[VV][VV + 1];   // sA[v][u] = A[v,u]
    __shared__ float sres[CC][VP];     // running residual slab (C x V)
    __shared__ float sy[CC][VP];       // A-mixed slab

    const int t = blockIdx.x;
    const int n = blockIdx.y;
    const int tid = threadIdx.x;

    // ---- load A (25x25) ----
    for (int i = tid; i < VV * VV; i += 256) {
        sA[i / VV][i % VV] = Amat[i];
    }

    // ---- load x slab: x[n][c][t][v], row stride T*V ----
    const float* xp = x + (size_t)n * CC * TT * VV + (size_t)t * VV;
    for (int i = tid; i < CC * VV; i += 256) {
        const int c = i / VV;
        const int v = i - c * VV;
        sres[c][v] = xp[(size_t)c * TT * VV + v];
    }
    __syncthreads();

    const float* const ws[4] = {w1, w2, w3, w4};
    const float* const bs[4] = {b1, b2, b3, b4};

    // GEMM thread tile: thread = (o-group, v-group)
    //   o rows: og and og+128 ; v range: vg=0 -> 0..12, vg=1 -> 12..24
    //   (overlap at v=12 is a benign duplicate: identical FP op order -> identical bits)
    const int og = tid >> 1;         // 0..127
    const int vg = tid & 1;
    const int vbeg = vg * 12;        // 0 or 12, 13 columns each

    #pragma unroll
    for (int blk = 0; blk < 4; ++blk) {
        const float* __restrict__ w = ws[blk];
        const float* __restrict__ bb = bs[blk];

        // ---- Phase A: sy[c][v] = sum_u A[v][u] * sres[c][u]; thread owns row c=tid
        {
            float r[VV];
            #pragma unroll
            for (int u = 0; u < VV; ++u) r[u] = sres[tid][u];
            #pragma unroll
            for (int v = 0; v < VV; ++v) {
                float acc = 0.f;
                #pragma unroll
                for (int u = 0; u < VV; ++u) acc = fmaf(sA[v][u], r[u], acc);
                sy[tid][v] = acc;
            }
        }
        __syncthreads();

        // ---- Phase G: out[o][v] = relu( sum_c w[o,c]*sy[c][v] + b[o] + sres[o][v] )
        float acc0[13], acc1[13];
        #pragma unroll
        for (int j = 0; j < 13; ++j) { acc0[j] = 0.f; acc1[j] = 0.f; }

        #pragma unroll 4
        for (int c = 0; c < CC; ++c) {
            const float wa = w[(size_t)og * CC + c];
            const float wb = w[(size_t)(og + 128) * CC + c];
            #pragma unroll
            for (int j = 0; j < 13; ++j) {
                const float yv = sy[c][vbeg + j];
                acc0[j] = fmaf(wa, yv, acc0[j]);
                acc1[j] = fmaf(wb, yv, acc1[j]);
            }
        }

        const float bias0 = bb[og];
        const float bias1 = bb[og + 128];
        float r0[13], r1[13];
        #pragma unroll
        for (int j = 0; j < 13; ++j) {
            r0[j] = sres[og][vbeg + j];
            r1[j] = sres[og + 128][vbeg + j];
        }
        __syncthreads();   // all reads of sres/sy done before overwrite
        #pragma unroll
        for (int j = 0; j < 13; ++j) {
            sres[og][vbeg + j]       = fmaxf(acc0[j] + bias0 + r0[j], 0.f);
            sres[og + 128][vbeg + j] = fmaxf(acc1[j] + bias1 + r1[j], 0.f);
        }
        __syncthreads();
    }

    // ---- store final slab ----
    float* op = out + (size_t)n * CC * TT * VV + (size_t)t * VV;
    for (int i = tid; i < CC * VV; i += 256) {
        const int c = i / VV;
        const int v = i - c * VV;
        op[(size_t)c * TT * VV + v] = sres[c][v];
    }
}

extern "C" void kernel_launch(void* const* d_in, const int* in_sizes, int n_in,
                              void* d_out, int out_size, void* d_ws, size_t ws_size,
                              hipStream_t stream) {
    // inputs: t(unused), x, A, w1,b1, w2,b2, w3,b3, w4,b4
    const float* x  = (const float*)d_in[1];
    const float* A  = (const float*)d_in[2];
    const float* w1 = (const float*)d_in[3];
    const float* b1 = (const float*)d_in[4];
    const float* w2 = (const float*)d_in[5];
    const float* b2 = (const float*)d_in[6];
    const float* w3 = (const float*)d_in[7];
    const float* b3 = (const float*)d_in[8];
    const float* w4 = (const float*)d_in[9];
    const float* b4 = (const float*)d_in[10];
    float* out = (float*)d_out;

    dim3 grid(TT, NN);   // one workgroup per (n,t) slab
    ode_fused<<<grid, 256, 0, stream>>>(x, A, w1, b1, w2, b2, w3, b3, w4, b4, out);
}

// Round 2
// 445.891 us; speedup vs baseline: 2.8284x; 2.8284x over previous
//
#include <hip/hip_runtime.h>
#include <math.h>

// Problem: N=64, C=256, T=64, V=25 graph-ODE, 4 fused blocks.
// Strategy: bf16 MFMA (32x32x16) for both einsums, fully fused per (n, t-pair)
// slab. S=2 slabs per WG to halve L2 traffic on w. fp32 accumulate throughout.
#define NN 64
#define CC 256
#define TT 64
#define VV 25

typedef __bf16 bf16;
typedef __attribute__((ext_vector_type(8)))  __bf16 bf16x8;
typedef __attribute__((ext_vector_type(4)))  __bf16 bf16x4;
typedef __attribute__((ext_vector_type(16))) float  f32x16;

// LDS row strides (in bf16 elements), chosen for 16B row alignment and
// uniform bank coverage (stride_dwords mod 32 in {20, 4} -> dense pattern):
#define RS 40    // sres: 80 B = 20 dwords
#define YS 264   // syT : 528 B = 132 dwords (132 % 32 == 4)
#define AS 40    // sAb : 80 B

// ---- pre-convert the four 256x256 fp32 w matrices to bf16 in d_ws ----
__global__ void convert_w(const float* __restrict__ w1, const float* __restrict__ w2,
                          const float* __restrict__ w3, const float* __restrict__ w4,
                          bf16* __restrict__ wb) {
    const int i = (blockIdx.x * 256 + threadIdx.x) * 4;   // 65536 threads x 4 elems
    const int blk = i >> 16;                               // uniform per block (1024 | 65536)
    const int off = i & 65535;
    const float* src = (blk == 0) ? w1 : (blk == 1) ? w2 : (blk == 2) ? w3 : w4;
    const float4 f = *(const float4*)(src + off);
    bf16x4 o;
    o[0] = (bf16)f.x; o[1] = (bf16)f.y; o[2] = (bf16)f.z; o[3] = (bf16)f.w;
    *(bf16x4*)(wb + i) = o;
}

#define MFMA(A, B, C) __builtin_amdgcn_mfma_f32_32x32x16_bf16(A, B, C, 0, 0, 0)

__global__ __launch_bounds__(256, 2) void ode_mfma(
    const float* __restrict__ x, const float* __restrict__ Amat,
    const bf16* __restrict__ wb,
    const float* __restrict__ b1, const float* __restrict__ b2,
    const float* __restrict__ b3, const float* __restrict__ b4,
    float* __restrict__ out)
{
    __shared__ bf16 sres[2][CC][RS];   // residual slabs, bf16 (u padded 25..31 = 0-by-construction not needed; sAb padding kills them)
    __shared__ bf16 syT [2][32][YS];   // y transposed: syT[s][v][c]
    __shared__ bf16 sAb [32][AS];      // A[v][u], zero-padded to 32x32 used region

    const int t0   = blockIdx.x * 2;   // slab pair (t0, t0+1), t0 even
    const int n    = blockIdx.y;
    const int tid  = threadIdx.x;
    const int wave = tid >> 6;
    const int lane = tid & 63;
    const int lh   = lane >> 5;        // half-wave select (k-split)
    const int l31  = lane & 31;

    // ---- stage A (zero-padded) : sAb[v][u] = (v<25 && u<25) ? A[v,u] : 0
    for (int i = tid; i < 32 * AS; i += 256) {
        const int v = i / AS, u = i - v * AS;
        sAb[v][u] = (v < VV && u < VV) ? (bf16)Amat[v * VV + u] : (bf16)0.f;
    }

    // ---- stage x slabs -> sres (bf16); zero the u=25..31 pad ----
    {
        const int c = tid;
        for (int s = 0; s < 2; ++s) {
            const float* src = x + (((size_t)n * CC + c) * TT + (t0 + s)) * VV;
            #pragma unroll
            for (int j = 0; j < 12; ++j) {           // 8B-aligned (t even -> 200B multiples)
                const float2 f = *(const float2*)(src + 2 * j);
                sres[s][c][2 * j]     = (bf16)f.x;
                sres[s][c][2 * j + 1] = (bf16)f.y;
            }
            sres[s][c][24] = (bf16)src[24];
            #pragma unroll
            for (int u = VV; u < 32; ++u) sres[s][c][u] = (bf16)0.f;
        }
    }
    __syncthreads();

    const float* const bs[4] = {b1, b2, b3, b4};

    for (int blk = 0; blk < 4; ++blk) {
        // ================= Phase A: y[c][v] = sum_u res[c][u] * A[v][u] ======
        // D(MxN)=A(MxK)B(KxN): M=c(32-tile), N=v(32), K=u(32, zero-padded).
        // B-frag: B[k][n] = A[n][k] -> sAb row n=l31, k contiguous.
        {
            const bf16x8 bf0 = *(const bf16x8*)&sAb[l31][lh * 8];
            const bf16x8 bf1 = *(const bf16x8*)&sAb[l31][16 + lh * 8];
            #pragma unroll
            for (int i = 0; i < 4; ++i) {
                const int idx = wave * 4 + i;      // 16 tiles: s = idx>>3, ct = idx&7
                const int s  = idx >> 3;
                const int ct = idx & 7;
                const bf16x8 af0 = *(const bf16x8*)&sres[s][ct * 32 + l31][lh * 8];
                const bf16x8 af1 = *(const bf16x8*)&sres[s][ct * 32 + l31][16 + lh * 8];
                f32x16 d = {};
                d = MFMA(af0, bf0, d);
                d = MFMA(af1, bf1, d);
                // D: col v = l31, row c = ct*32 + (reg&3) + 8*(reg>>2) + 4*lh
                #pragma unroll
                for (int g = 0; g < 4; ++g) {
                    bf16x4 p;
                    p[0] = (bf16)d[4 * g];     p[1] = (bf16)d[4 * g + 1];
                    p[2] = (bf16)d[4 * g + 2]; p[3] = (bf16)d[4 * g + 3];
                    *(bf16x4*)&syT[s][l31][ct * 32 + 8 * g + 4 * lh] = p;
                }
            }
        }
        __syncthreads();

        // ================= Phase G: out[o][v] = relu(sum_c w[o,c] y[c][v] + b[o] + res[o][v])
        // A-frag: w[o][c] (global bf16), B-frag: y[c][v] = syT[v][c].
        const bf16* wmat = wb + (size_t)blk * CC * CC;
        const float* bias = bs[blk];
        const int o0 = wave * 64;

        f32x16 acc00 = {}, acc01 = {}, acc10 = {}, acc11 = {};
        #pragma unroll 4
        for (int k = 0; k < 16; ++k) {
            const int c0 = k * 16 + lh * 8;
            const bf16x8 a0 = *(const bf16x8*)(wmat + (size_t)(o0 + l31) * CC + c0);
            const bf16x8 a1 = *(const bf16x8*)(wmat + (size_t)(o0 + 32 + l31) * CC + c0);
            const bf16x8 y0 = *(const bf16x8*)&syT[0][l31][c0];
            const bf16x8 y1 = *(const bf16x8*)&syT[1][l31][c0];
            acc00 = MFMA(a0, y0, acc00);
            acc01 = MFMA(a0, y1, acc01);
            acc10 = MFMA(a1, y0, acc10);
            acc11 = MFMA(a1, y1, acc11);
        }

        // epilogue: bias + residual + relu; write residual (blk<3) or out (blk==3)
        const int v = l31;
        #define EPILOGUE(ACC, OT, S)                                                   \
            _Pragma("unroll")                                                          \
            for (int reg = 0; reg < 16; ++reg) {                                       \
                const int o = o0 + (OT) * 32 + (reg & 3) + 8 * (reg >> 2) + 4 * lh;    \
                float val = ACC[reg] + bias[o] + (float)sres[S][o][v];                 \
                val = fmaxf(val, 0.f);                                                 \
                if (v < VV) {                                                          \
                    if (blk < 3) sres[S][o][v] = (bf16)val;                            \
                    else out[(((size_t)n * CC + o) * TT + (t0 + (S))) * VV + v] = val; \
                }                                                                      \
            }
        EPILOGUE(acc00, 0, 0)
        EPILOGUE(acc01, 0, 1)
        EPILOGUE(acc10, 1, 0)
        EPILOGUE(acc11, 1, 1)
        #undef EPILOGUE
        __syncthreads();
    }
}

extern "C" void kernel_launch(void* const* d_in, const int* in_sizes, int n_in,
                              void* d_out, int out_size, void* d_ws, size_t ws_size,
                              hipStream_t stream) {
    // inputs: t(unused), x, A, w1,b1, w2,b2, w3,b3, w4,b4
    const float* x  = (const float*)d_in[1];
    const float* A  = (const float*)d_in[2];
    const float* w1 = (const float*)d_in[3];
    const float* b1 = (const float*)d_in[4];
    const float* w2 = (const float*)d_in[5];
    const float* b2 = (const float*)d_in[6];
    const float* w3 = (const float*)d_in[7];
    const float* b3 = (const float*)d_in[8];
    const float* w4 = (const float*)d_in[9];
    const float* b4 = (const float*)d_in[10];
    float* out = (float*)d_out;
    bf16* wb = (bf16*)d_ws;   // 4*256*256*2 = 512 KB

    convert_w<<<256, 256, 0, stream>>>(w1, w2, w3, w4, wb);
    dim3 grid(TT / 2, NN);    // one WG per (n, t-pair): 2048 WGs
    ode_mfma<<<grid, 256, 0, stream>>>(x, A, wb, b1, b2, b3, b4, out);
}

// Round 3
// 411.167 us; speedup vs baseline: 3.0673x; 1.0845x over previous
//
#include <hip/hip_runtime.h>
#include <math.h>

// Problem: N=64, C=256, T=64, V=25 graph-ODE, 4 fused blocks.
// bf16 MFMA 32x32x16 for both einsums, fused per (n, t-pair) slab; S=2 slabs/WG.
// R3: w pre-packed into MFMA-fragment order (coalesced 16B/lane loads),
//     coalesced x staging, biases staged in LDS.
#define NN 64
#define CC 256
#define TT 64
#define VV 25

typedef __bf16 bf16;
typedef __attribute__((ext_vector_type(8)))  __bf16 bf16x8;
typedef __attribute__((ext_vector_type(4)))  __bf16 bf16x4;
typedef __attribute__((ext_vector_type(16))) float  f32x16;

#define RS 40    // sres row stride (bf16): 80 B, 16B-aligned rows
#define YS 264   // syT row stride (bf16): 528 B = 132 dw (4-way worst on b128 reads)
#define AS 40

// ---- pre-pack the four 256x256 fp32 w matrices into bf16 MFMA-fragment order.
// Layout: wp[((blk*4+wave)*16+k)*1024 + pair*512 + lane*8 + e]
//   = w_blk[wave*64 + pair*32 + (lane&31)][k*16 + (lane>>5)*8 + e]
// so the GEMM's per-k A-fragment load is base + k*1024 (+512) + lane*8: 16B/lane coalesced.
__global__ void convert_w(const float* __restrict__ w1, const float* __restrict__ w2,
                          const float* __restrict__ w3, const float* __restrict__ w4,
                          bf16* __restrict__ wp) {
    const int gid = blockIdx.x * 256 + threadIdx.x;   // 0..32767
    const int lane = gid & 63;
    const int pair = (gid >> 6) & 1;
    const int k    = (gid >> 7) & 15;
    const int wv   = (gid >> 11) & 3;
    const int blk  = gid >> 13;
    const float* src = (blk == 0) ? w1 : (blk == 1) ? w2 : (blk == 2) ? w3 : w4;
    const int row = wv * 64 + pair * 32 + (lane & 31);
    const int col = k * 16 + (lane >> 5) * 8;
    const float4 f0 = *(const float4*)(src + row * CC + col);
    const float4 f1 = *(const float4*)(src + row * CC + col + 4);
    bf16x8 o;
    o[0] = (bf16)f0.x; o[1] = (bf16)f0.y; o[2] = (bf16)f0.z; o[3] = (bf16)f0.w;
    o[4] = (bf16)f1.x; o[5] = (bf16)f1.y; o[6] = (bf16)f1.z; o[7] = (bf16)f1.w;
    *(bf16x8*)(wp + (size_t)gid * 8) = o;
}

#define MFMA(A, B, C) __builtin_amdgcn_mfma_f32_32x32x16_bf16(A, B, C, 0, 0, 0)

__global__ __launch_bounds__(256, 2) void ode_mfma(
    const float* __restrict__ x, const float* __restrict__ Amat,
    const bf16* __restrict__ wp,
    const float* __restrict__ b1, const float* __restrict__ b2,
    const float* __restrict__ b3, const float* __restrict__ b4,
    float* __restrict__ out)
{
    __shared__ bf16  sres[2][CC][RS];
    __shared__ bf16  syT [2][32][YS];
    __shared__ bf16  sAb [32][AS];
    __shared__ float sbias[4][CC];

    const int t0   = blockIdx.x * 2;
    const int n    = blockIdx.y;
    const int tid  = threadIdx.x;
    const int wave = tid >> 6;
    const int lane = tid & 63;
    const int lh   = lane >> 5;
    const int l31  = lane & 31;

    // ---- stage biases (coalesced) ----
    sbias[0][tid] = b1[tid];
    sbias[1][tid] = b2[tid];
    sbias[2][tid] = b3[tid];
    sbias[3][tid] = b4[tid];

    // ---- stage A (zero-padded to 32x32) ----
    for (int i = tid; i < 32 * AS; i += 256) {
        const int v = i / AS, u = i - v * AS;
        sAb[v][u] = (v < VV && u < VV) ? (bf16)Amat[v * VV + u] : (bf16)0.f;
    }

    // ---- stage x slabs, coalesced: rows c hold 50 contiguous floats (t0,t0+1) ----
    {
        const float* xb = x + ((size_t)n * CC * TT + t0) * VV;  // + c*TT*VV + f
        #pragma unroll
        for (int it = 0; it < 25; ++it) {
            const int g2 = tid + it * 256;          // float2 index, 0..6399
            const int c = g2 / 25;
            const int off2 = g2 - c * 25;
            const float2 f = *(const float2*)(xb + (size_t)c * TT * VV + off2 * 2);
            const int f0 = off2 * 2;
            if (f0 < 24) {
                sres[0][c][f0]     = (bf16)f.x;
                sres[0][c][f0 + 1] = (bf16)f.y;
            } else if (f0 == 24) {
                sres[0][c][24] = (bf16)f.x;
                sres[1][c][0]  = (bf16)f.y;
            } else {
                sres[1][c][f0 - 25] = (bf16)f.x;
                sres[1][c][f0 - 24] = (bf16)f.y;
            }
        }
        for (int i = tid; i < 2 * CC; i += 256) {
            const int s = i >> 8, c = i & 255;
            #pragma unroll
            for (int u = VV; u < 32; ++u) sres[s][c][u] = (bf16)0.f;
        }
    }
    __syncthreads();

    for (int blk = 0; blk < 4; ++blk) {
        // ===== Phase A: y[c][v] = sum_u res[c][u] * A[v][u] =====
        {
            const bf16x8 bf0 = *(const bf16x8*)&sAb[l31][lh * 8];
            const bf16x8 bf1 = *(const bf16x8*)&sAb[l31][16 + lh * 8];
            #pragma unroll
            for (int i = 0; i < 4; ++i) {
                const int idx = wave * 4 + i;
                const int s  = idx >> 3;
                const int ct = idx & 7;
                const bf16x8 af0 = *(const bf16x8*)&sres[s][ct * 32 + l31][lh * 8];
                const bf16x8 af1 = *(const bf16x8*)&sres[s][ct * 32 + l31][16 + lh * 8];
                f32x16 d = {};
                d = MFMA(af0, bf0, d);
                d = MFMA(af1, bf1, d);
                #pragma unroll
                for (int g = 0; g < 4; ++g) {
                    bf16x4 p;
                    p[0] = (bf16)d[4 * g];     p[1] = (bf16)d[4 * g + 1];
                    p[2] = (bf16)d[4 * g + 2]; p[3] = (bf16)d[4 * g + 3];
                    *(bf16x4*)&syT[s][l31][ct * 32 + 8 * g + 4 * lh] = p;
                }
            }
        }
        __syncthreads();

        // ===== Phase G: out[o][v] = relu(sum_c w[o,c] y[c][v] + b[o] + res[o][v]) =====
        // A-frags from pre-packed wp: 16 B/lane fully coalesced.
        const bf16* wbase = wp + ((size_t)(blk * 4 + wave) * 16) * 1024 + lane * 8;
        const int o0 = wave * 64;

        f32x16 acc00 = {}, acc01 = {}, acc10 = {}, acc11 = {};
        #pragma unroll 4
        for (int k = 0; k < 16; ++k) {
            const int c0 = k * 16 + lh * 8;
            const bf16x8 a0 = *(const bf16x8*)(wbase + k * 1024);
            const bf16x8 a1 = *(const bf16x8*)(wbase + k * 1024 + 512);
            const bf16x8 y0 = *(const bf16x8*)&syT[0][l31][c0];
            const bf16x8 y1 = *(const bf16x8*)&syT[1][l31][c0];
            acc00 = MFMA(a0, y0, acc00);
            acc01 = MFMA(a0, y1, acc01);
            acc10 = MFMA(a1, y0, acc10);
            acc11 = MFMA(a1, y1, acc11);
        }

        const int v = l31;
        #define EPILOGUE(ACC, OT, S)                                                    \
            _Pragma("unroll")                                                           \
            for (int g = 0; g < 4; ++g) {                                               \
                const int ob = o0 + (OT) * 32 + 8 * g + 4 * lh;                         \
                const float4 bq = *(const float4*)&sbias[blk][ob];                      \
                _Pragma("unroll")                                                       \
                for (int r = 0; r < 4; ++r) {                                           \
                    const int o = ob + r;                                               \
                    float val = ACC[4 * g + r] + ((const float*)&bq)[r]                 \
                              + (float)sres[S][o][v];                                   \
                    val = fmaxf(val, 0.f);                                              \
                    if (v < VV) {                                                       \
                        if (blk < 3) sres[S][o][v] = (bf16)val;                         \
                        else out[(((size_t)n * CC + o) * TT + (t0 + (S))) * VV + v] = val; \
                    }                                                                   \
                }                                                                       \
            }
        EPILOGUE(acc00, 0, 0)
        EPILOGUE(acc01, 0, 1)
        EPILOGUE(acc10, 1, 0)
        EPILOGUE(acc11, 1, 1)
        #undef EPILOGUE
        __syncthreads();
    }
}

extern "C" void kernel_launch(void* const* d_in, const int* in_sizes, int n_in,
                              void* d_out, int out_size, void* d_ws, size_t ws_size,
                              hipStream_t stream) {
    const float* x  = (const float*)d_in[1];
    const float* A  = (const float*)d_in[2];
    const float* w1 = (const float*)d_in[3];
    const float* b1 = (const float*)d_in[4];
    const float* w2 = (const float*)d_in[5];
    const float* b2 = (const float*)d_in[6];
    const float* w3 = (const float*)d_in[7];
    const float* b3 = (const float*)d_in[8];
    const float* w4 = (const float*)d_in[9];
    const float* b4 = (const float*)d_in[10];
    float* out = (float*)d_out;
    bf16* wp = (bf16*)d_ws;   // 512 KB packed fragments

    convert_w<<<128, 256, 0, stream>>>(w1, w2, w3, w4, wp);
    dim3 grid(TT / 2, NN);
    ode_mfma<<<grid, 256, 0, stream>>>(x, A, wp, b1, b2, b3, b4, out);
}

// Round 4
// 380.030 us; speedup vs baseline: 3.3186x; 1.0819x over previous
//
#include <hip/hip_runtime.h>
#include <math.h>

// N=64, C=256, T=64, V=25 graph-ODE, 4 fused blocks. bf16 MFMA 32x32x16.
// R4: S=1 slab/WG + manual 40.3 KB LDS layout -> 4 WGs/CU (occupancy 2x).
#define NN 64
#define CC 256
#define TT 64
#define VV 25

typedef __bf16 bf16;
typedef __attribute__((ext_vector_type(8)))  __bf16 bf16x8;
typedef __attribute__((ext_vector_type(4)))  __bf16 bf16x4;
typedef __attribute__((ext_vector_type(16))) float  f32x16;

#define RS 40    // sres row stride (bf16): 80 B
#define YS 264   // syT row stride (bf16): 528 B

// Manual LDS layout (bytes). syT declared 26 rows; reads from lanes 26..31
// overrun into sAb/sbias (read-only after staging; results masked) - by design.
#define OFF_SRES  0        // 256*40*2  = 20480
#define OFF_SYT   20480    // 26*264*2  = 13728
#define OFF_SAB   34208    // 32*32*2   = 2048
#define OFF_SBIAS 36256    // 4*256*4   = 4096
#define SMEM_BYTES 40352   // <= 40960 -> 4 WGs/CU

// ---- pack the four 256x256 fp32 w into bf16 MFMA A-fragment order ----
// wp[((blk*4+wv)*16+k)*1024 + pair*512 + lane*8 + e]
//   = w_blk[wv*64+pair*32+(lane&31)][k*16+(lane>>5)*8+e]
__global__ void convert_w(const float* __restrict__ w1, const float* __restrict__ w2,
                          const float* __restrict__ w3, const float* __restrict__ w4,
                          bf16* __restrict__ wp) {
    const int gid = blockIdx.x * 256 + threadIdx.x;   // 0..32767
    const int e8  = gid * 8;                          // linear over 4*65536 elems
    const int blk = e8 >> 16;
    const int off = e8 & 65535;
    const int row = off >> 8;
    const int col = off & 255;
    const float* src = (blk == 0) ? w1 : (blk == 1) ? w2 : (blk == 2) ? w3 : w4;
    const float4 f0 = *(const float4*)(src + off);        // coalesced reads
    const float4 f1 = *(const float4*)(src + off + 4);
    bf16x8 o;
    o[0] = (bf16)f0.x; o[1] = (bf16)f0.y; o[2] = (bf16)f0.z; o[3] = (bf16)f0.w;
    o[4] = (bf16)f1.x; o[5] = (bf16)f1.y; o[6] = (bf16)f1.z; o[7] = (bf16)f1.w;
    const int wv = row >> 6, pair = (row >> 5) & 1, l31 = row & 31;
    const int k = col >> 4, lh = (col >> 3) & 1;
    wp += (((size_t)(blk * 4 + wv) * 16 + k) * 1024) + pair * 512 + (lh * 32 + l31) * 8;
    *(bf16x8*)wp = o;
}

#define MFMA(A, B, C) __builtin_amdgcn_mfma_f32_32x32x16_bf16(A, B, C, 0, 0, 0)

__global__ __launch_bounds__(256, 4) void ode_mfma(
    const float* __restrict__ x, const float* __restrict__ Amat,
    const bf16* __restrict__ wp,
    const float* __restrict__ b1, const float* __restrict__ b2,
    const float* __restrict__ b3, const float* __restrict__ b4,
    float* __restrict__ out)
{
    __shared__ __attribute__((aligned(16))) char smem[SMEM_BYTES];
    bf16*  sres  = (bf16*)(smem + OFF_SRES);    // [c][RS]
    bf16*  syT   = (bf16*)(smem + OFF_SYT);     // [v][YS]
    bf16*  sAb   = (bf16*)(smem + OFF_SAB);     // [v][32]
    float* sbias = (float*)(smem + OFF_SBIAS);  // [4][CC]

    const int t    = blockIdx.x;
    const int n    = blockIdx.y;
    const int tid  = threadIdx.x;
    const int wave = tid >> 6;
    const int lane = tid & 63;
    const int lh   = lane >> 5;
    const int l31  = lane & 31;

    // ---- stage biases (coalesced) ----
    sbias[0 * CC + tid] = b1[tid];
    sbias[1 * CC + tid] = b2[tid];
    sbias[2 * CC + tid] = b3[tid];
    sbias[3 * CC + tid] = b4[tid];

    // ---- stage A, zero-padded to 32x32 ----
    for (int i = tid; i < 32 * 32; i += 256) {
        const int v = i >> 5, u = i & 31;
        sAb[i] = (v < VV && u < VV) ? (bf16)Amat[v * VV + u] : (bf16)0.f;
    }

    // ---- stage x slab (mostly-coalesced scalar; odd t breaks 8B alignment) ----
    {
        const float* xb = x + ((size_t)n * CC * TT + t) * VV;  // + c*T*V + v
        for (int i = tid; i < CC * VV; i += 256) {
            const int c = i / VV;
            const int v = i - c * VV;
            sres[c * RS + v] = (bf16)xb[(size_t)c * TT * VV + v];
        }
        #pragma unroll
        for (int u = VV; u < 32; ++u) sres[tid * RS + u] = (bf16)0.f;  // tid == c
    }
    __syncthreads();

    // A-matrix B-fragments are constant across blocks: hoist.
    const bf16x8 bfA0 = *(const bf16x8*)&sAb[l31 * 32 + lh * 8];
    const bf16x8 bfA1 = *(const bf16x8*)&sAb[l31 * 32 + 16 + lh * 8];

    for (int blk = 0; blk < 4; ++blk) {
        // ===== Phase A: yT[v][c] = sum_u res[c][u] * A[v][u]; 2 c-tiles/wave =====
        #pragma unroll
        for (int i = 0; i < 2; ++i) {
            const int ct = wave * 2 + i;
            const bf16x8 af0 = *(const bf16x8*)&sres[(ct * 32 + l31) * RS + lh * 8];
            const bf16x8 af1 = *(const bf16x8*)&sres[(ct * 32 + l31) * RS + 16 + lh * 8];
            f32x16 d = {};
            d = MFMA(af0, bfA0, d);
            d = MFMA(af1, bfA1, d);
            // D: col v = l31, row c = ct*32 + (reg&3) + 8*(reg>>2) + 4*lh
            if (l31 < VV) {
                #pragma unroll
                for (int g = 0; g < 4; ++g) {
                    bf16x4 p;
                    p[0] = (bf16)d[4 * g];     p[1] = (bf16)d[4 * g + 1];
                    p[2] = (bf16)d[4 * g + 2]; p[3] = (bf16)d[4 * g + 3];
                    *(bf16x4*)&syT[l31 * YS + ct * 32 + 8 * g + 4 * lh] = p;
                }
            }
        }
        __syncthreads();

        // ===== Phase G: out[o][v] = relu(sum_c w[o,c] y[c][v] + b[o] + res[o][v]) =====
        const bf16* wbase = wp + ((size_t)(blk * 4 + wave) * 16) * 1024 + lane * 8;
        const int o0 = wave * 64;

        f32x16 acc0 = {}, acc1 = {};
        #pragma unroll 4
        for (int k = 0; k < 16; ++k) {
            const bf16x8 y0 = *(const bf16x8*)&syT[l31 * YS + k * 16 + lh * 8];
            const bf16x8 a0 = *(const bf16x8*)(wbase + k * 1024);
            const bf16x8 a1 = *(const bf16x8*)(wbase + k * 1024 + 512);
            acc0 = MFMA(a0, y0, acc0);
            acc1 = MFMA(a1, y0, acc1);
        }

        const int v = l31;
        #define EPILOGUE(ACC, OT)                                                   \
            _Pragma("unroll")                                                       \
            for (int g = 0; g < 4; ++g) {                                           \
                const int ob = o0 + (OT) * 32 + 8 * g + 4 * lh;                     \
                const float4 bq = *(const float4*)&sbias[blk * CC + ob];            \
                _Pragma("unroll")                                                   \
                for (int r = 0; r < 4; ++r) {                                       \
                    const int o = ob + r;                                           \
                    float val = ACC[4 * g + r] + ((const float*)&bq)[r]             \
                              + (float)sres[o * RS + v];                            \
                    val = fmaxf(val, 0.f);                                          \
                    if (v < VV) {                                                   \
                        if (blk < 3) sres[o * RS + v] = (bf16)val;                  \
                        else out[(((size_t)n * CC + o) * TT + t) * VV + v] = val;   \
                    }                                                               \
                }                                                                   \
            }
        EPILOGUE(acc0, 0)
        EPILOGUE(acc1, 1)
        #undef EPILOGUE
        __syncthreads();
    }
}

extern "C" void kernel_launch(void* const* d_in, const int* in_sizes, int n_in,
                              void* d_out, int out_size, void* d_ws, size_t ws_size,
                              hipStream_t stream) {
    const float* x  = (const float*)d_in[1];
    const float* A  = (const float*)d_in[2];
    const float* w1 = (const float*)d_in[3];
    const float* b1 = (const float*)d_in[4];
    const float* w2 = (const float*)d_in[5];
    const float* b2 = (const float*)d_in[6];
    const float* w3 = (const float*)d_in[7];
    const float* b3 = (const float*)d_in[8];
    const float* w4 = (const float*)d_in[9];
    const float* b4 = (const float*)d_in[10];
    float* out = (float*)d_out;
    bf16* wp = (bf16*)d_ws;   // 512 KB packed w fragments

    convert_w<<<128, 256, 0, stream>>>(w1, w2, w3, w4, wp);
    dim3 grid(TT, NN);        // one WG per (n,t) slab: 4096 WGs
    ode_mfma<<<grid, 256, 0, stream>>>(x, A, wp, b1, b2, b3, b4, out);
}